// Round 2
// baseline (241.124 us; speedup 1.0000x reference)
//
#include <hip/hip_runtime.h>
#include <math.h>

#define ALPHA 0.2f

static constexpr int NN = 8, HH = 64, WW = 64, TT = 32, VV = 32, FF = 32;

// workspace layout (float offsets)
static constexpr size_t WS_ADJ = 0;      // 1024: adj_n [i][j]
static constexpr size_t WS_WA1 = 1024;   // 32: W_map @ a1
static constexpr size_t WS_WA2 = 1056;   // 32: W_map @ a2
static constexpr size_t WS_C12 = 1088;   // 2: b.a1, b.a2
static constexpr size_t WS_S1  = 2048;                         // N*H*W*V = 1048576, [n][h][w][i]
static constexpr size_t WS_S2  = WS_S1 + (size_t)NN*HH*WW*VV;  // same
static constexpr size_t WS_DEN = WS_S2 + (size_t)NN*HH*WW*VV;  // N*H*V*V = 524288, [n][h][i][j] = 1/denom

__global__ __launch_bounds__(1024) void k0_prep(const float* __restrict__ W_map,
    const float* __restrict__ b_map, const float* __restrict__ a_attn,
    const float* __restrict__ B_adj, float* __restrict__ ws)
{
    __shared__ float lds[1024];
    __shared__ float d12[32];
    int tid = threadIdx.x;
    int i = tid >> 5, j = tid & 31;
    float a = B_adj[tid] + (i == j ? 1.0f : 0.0f);
    lds[tid] = a; __syncthreads();
    for (int s = 512; s > 0; s >>= 1) { if (tid < s) lds[tid] = fmaxf(lds[tid], lds[tid + s]); __syncthreads(); }
    float mx = lds[0]; __syncthreads();
    lds[tid] = a; __syncthreads();
    for (int s = 512; s > 0; s >>= 1) { if (tid < s) lds[tid] = fminf(lds[tid], lds[tid + s]); __syncthreads(); }
    float mn = lds[0]; __syncthreads();
    float nrm = (a - mn) / (mx - mn);
    lds[tid] = nrm; __syncthreads();
    if (tid < 32) {
        float s = 0.f;
        for (int jj = 0; jj < 32; ++jj) s += lds[tid * 32 + jj];
        d12[tid] = 1.0f / sqrtf(s);
    }
    __syncthreads();
    ws[WS_ADJ + tid] = d12[i] * nrm * d12[j];
    if (tid < 32) {
        float w1 = 0.f, w2 = 0.f;
        for (int f = 0; f < 32; ++f) {
            w1 += W_map[tid * 32 + f] * a_attn[f];
            w2 += W_map[tid * 32 + f] * a_attn[32 + f];
        }
        ws[WS_WA1 + tid] = w1; ws[WS_WA2 + tid] = w2;
    }
    if (tid == 0) {
        float c1 = 0.f, c2 = 0.f;
        for (int f = 0; f < 32; ++f) { c1 += b_map[f] * a_attn[f]; c2 += b_map[f] * a_attn[32 + f]; }
        ws[WS_C12] = c1; ws[WS_C12 + 1] = c2;
    }
}

// s1[n,i,h,w] = sum_t h[n,h,w,t,i] * wa1[t] + c1   stored [n][h][w][i]
__global__ __launch_bounds__(256) void k1_scores(const float* __restrict__ hin, float* __restrict__ ws)
{
    __shared__ float lwa1[32], lwa2[32];
    int tid = threadIdx.x;
    if (tid < 32) lwa1[tid] = ws[WS_WA1 + tid];
    else if (tid < 64) lwa2[tid - 32] = ws[WS_WA2 + (tid - 32)];
    __syncthreads();
    float c1 = ws[WS_C12], c2 = ws[WS_C12 + 1];
    int g = tid >> 5, lane = tid & 31;
    long site = (long)blockIdx.x * 8 + g;      // (n*64+h)*64 + w
    const float* hp = hin + site * 1024;       // [t][v]
    float a1 = c1, a2 = c2;
#pragma unroll
    for (int t = 0; t < 32; ++t) {
        float x = hp[t * 32 + lane];
        a1 = fmaf(x, lwa1[t], a1);
        a2 = fmaf(x, lwa2[t], a2);
    }
    ws[WS_S1 + site * 32 + lane] = a1;
    ws[WS_S2 + site * 32 + lane] = a2;
}

// rden[n,h,i,j] = 1 / sum_w exp(lrelu(s1[i,w]+s2[j,w]))
__global__ __launch_bounds__(1024) void k2_denom(float* __restrict__ ws)
{
    __shared__ float ls1[2048], ls2[2048];  // [w][i]
    int tid = threadIdx.x;
    long nh = blockIdx.x;
    const float* s1 = ws + WS_S1 + nh * 2048;
    const float* s2 = ws + WS_S2 + nh * 2048;
    ls1[tid] = s1[tid]; ls1[tid + 1024] = s1[tid + 1024];
    ls2[tid] = s2[tid]; ls2[tid + 1024] = s2[tid + 1024];
    __syncthreads();
    int i = tid >> 5, j = tid & 31;
    float sum = 0.f;
#pragma unroll
    for (int w = 0; w < 64; ++w) {
        float e = ls1[w * 32 + i] + ls2[w * 32 + j];
        e = e > 0.f ? e : ALPHA * e;
        sum += __expf(e);
    }
    ws[WS_DEN + nh * 1024 + tid] = 1.0f / sum;
}

__device__ __forceinline__ float elu(float x) { return x > 0.f ? x : expm1f(x); }

// One site per WAVE. 8x8 lane grid, each lane owns a 4x4 register tile of each
// 32x32 matmul. Per k-step: 2x ds_read_b128 (broadcast, conflict-free) + 16 FMA.
__global__ __launch_bounds__(128) void k3_main(const float* __restrict__ hin,
    const float* __restrict__ W_map, const float* __restrict__ b_map,
    const float* __restrict__ ws, float* __restrict__ out)
{
    __shared__ float wm[1024];        // [t][f]
    __shared__ float adjs[1024];      // [i][j]
    __shared__ float bufA[2][1024];   // per-wave: ht [t][v]  ->  at [i][j']
    __shared__ float bufW[2][1024];   // per-wave: Wh [j'][f]
    __shared__ float bufM[2][1024];   // per-wave: M  [j'][j]
    const int tid = threadIdx.x;
    const int wid = tid >> 6, lane = tid & 63;
    const long site = (long)blockIdx.x * 2 + wid;   // (n*64+h)*64 + w
    const int w = (int)(site & 63);
    const long nh = site >> 6;
    const int hh = (int)(nh & 63);
    const int n = (int)(nh >> 6);
    const int r0 = (lane >> 3) << 2;   // row-range base (4 rows)
    const int c0 = (lane & 7) << 2;    // col-range base (4 cols)

    // stage shared (whole block) + per-wave ht
    ((float4*)wm)[tid]         = ((const float4*)W_map)[tid];
    ((float4*)wm)[tid + 128]   = ((const float4*)W_map)[tid + 128];
    ((float4*)adjs)[tid]       = ((const float4*)(ws + WS_ADJ))[tid];
    ((float4*)adjs)[tid + 128] = ((const float4*)(ws + WS_ADJ))[tid + 128];
    {
        const float4* hs = (const float4*)(hin + site * 1024);
        float4* hd = (float4*)bufA[wid];
        hd[lane]       = hs[lane];
        hd[lane + 64]  = hs[lane + 64];
        hd[lane + 128] = hs[lane + 128];
        hd[lane + 192] = hs[lane + 192];
    }
    __syncthreads();

    float acc[4][4];

    // Phase 1: Wh[j][f] = sum_t ht[t][j]*wm[t][f] + b[f]   (thread: j=r0.., f=c0..)
    {
        const float4 bv = *(const float4*)(b_map + c0);
#pragma unroll
        for (int r = 0; r < 4; ++r) { acc[r][0] = bv.x; acc[r][1] = bv.y; acc[r][2] = bv.z; acc[r][3] = bv.w; }
#pragma unroll
        for (int t = 0; t < 32; ++t) {
            const float4 a = *(const float4*)&bufA[wid][t * 32 + r0];
            const float4 b = *(const float4*)&wm[t * 32 + c0];
            const float ar[4] = { a.x, a.y, a.z, a.w };
            const float bc[4] = { b.x, b.y, b.z, b.w };
#pragma unroll
            for (int r = 0; r < 4; ++r)
#pragma unroll
                for (int c = 0; c < 4; ++c) acc[r][c] = fmaf(ar[r], bc[c], acc[r][c]);
        }
#pragma unroll
        for (int r = 0; r < 4; ++r)
            *(float4*)&bufW[wid][(r0 + r) * 32 + c0] = make_float4(acc[r][0], acc[r][1], acc[r][2], acc[r][3]);
    }
    __syncthreads();

    // Phase 2: at[i][j'] = exp(lrelu(s1[i]+s2[j'])) * rden[i][j']   (thread: i=r0.., j'=c0..)
    {
        const float* s1p  = ws + WS_S1 + site * 32;
        const float* s2p  = ws + WS_S2 + site * 32;
        const float* denp = ws + WS_DEN + nh * 1024;
        const float4 s1q = *(const float4*)(s1p + r0);
        const float4 s2q = *(const float4*)(s2p + c0);
        const float s1a[4] = { s1q.x, s1q.y, s1q.z, s1q.w };
        const float s2a[4] = { s2q.x, s2q.y, s2q.z, s2q.w };
#pragma unroll
        for (int r = 0; r < 4; ++r) {
            const float4 rd = *(const float4*)(denp + (r0 + r) * 32 + c0);
            const float rda[4] = { rd.x, rd.y, rd.z, rd.w };
            float ov[4];
#pragma unroll
            for (int c = 0; c < 4; ++c) {
                float e = s1a[r] + s2a[c];
                e = e > 0.f ? e : ALPHA * e;
                ov[c] = __expf(e) * rda[c];
            }
            *(float4*)&bufA[wid][(r0 + r) * 32 + c0] = make_float4(ov[0], ov[1], ov[2], ov[3]);
        }
    }
    __syncthreads();

    // Phase 3: M[j'][j] = sum_i at[i][j']*adj[i][j]   (thread: j'=r0.., j=c0..)
    {
#pragma unroll
        for (int r = 0; r < 4; ++r)
#pragma unroll
            for (int c = 0; c < 4; ++c) acc[r][c] = 0.f;
#pragma unroll
        for (int i = 0; i < 32; ++i) {
            const float4 a = *(const float4*)&bufA[wid][i * 32 + r0];
            const float4 b = *(const float4*)&adjs[i * 32 + c0];
            const float ar[4] = { a.x, a.y, a.z, a.w };
            const float bc[4] = { b.x, b.y, b.z, b.w };
#pragma unroll
            for (int r = 0; r < 4; ++r)
#pragma unroll
                for (int c = 0; c < 4; ++c) acc[r][c] = fmaf(ar[r], bc[c], acc[r][c]);
        }
#pragma unroll
        for (int r = 0; r < 4; ++r)
            *(float4*)&bufM[wid][(r0 + r) * 32 + c0] = make_float4(acc[r][0], acc[r][1], acc[r][2], acc[r][3]);
    }
    __syncthreads();

    // Phase 4: O[f][j] = sum_j' Wh[j'][f]*M[j'][j]   (thread: f=r0.., j=c0..)
    {
#pragma unroll
        for (int r = 0; r < 4; ++r)
#pragma unroll
            for (int c = 0; c < 4; ++c) acc[r][c] = 0.f;
#pragma unroll
        for (int jp = 0; jp < 32; ++jp) {
            const float4 a = *(const float4*)&bufW[wid][jp * 32 + r0];
            const float4 b = *(const float4*)&bufM[wid][jp * 32 + c0];
            const float ar[4] = { a.x, a.y, a.z, a.w };
            const float bc[4] = { b.x, b.y, b.z, b.w };
#pragma unroll
            for (int r = 0; r < 4; ++r)
#pragma unroll
                for (int c = 0; c < 4; ++c) acc[r][c] = fmaf(ar[r], bc[c], acc[r][c]);
        }
        const int hhi = hh >> 5, f3 = hh & 31;
#pragma unroll
        for (int r = 0; r < 4; ++r) {
            const int f = r0 + r;
            const int w3 = f * 2 + hhi;
            float4 o;
            o.x = elu(acc[r][0]); o.y = elu(acc[r][1]); o.z = elu(acc[r][2]); o.w = elu(acc[r][3]);
            *(float4*)(out + ((((long)n * 64 + w) * 64 + w3) * 32 + f3) * 32 + c0) = o;
        }
    }
}

extern "C" void kernel_launch(void* const* d_in, const int* in_sizes, int n_in,
                              void* d_out, int out_size, void* d_ws, size_t ws_size,
                              hipStream_t stream) {
    (void)in_sizes; (void)n_in; (void)out_size; (void)ws_size;
    const float* hin    = (const float*)d_in[0];
    const float* W_map  = (const float*)d_in[1];
    const float* b_map  = (const float*)d_in[2];
    const float* a_attn = (const float*)d_in[3];
    const float* B_adj  = (const float*)d_in[4];
    float* out = (float*)d_out;
    float* ws  = (float*)d_ws;

    hipLaunchKernelGGL(k0_prep,   dim3(1),     dim3(1024), 0, stream, W_map, b_map, a_attn, B_adj, ws);
    hipLaunchKernelGGL(k1_scores, dim3(4096),  dim3(256),  0, stream, hin, ws);
    hipLaunchKernelGGL(k2_denom,  dim3(512),   dim3(1024), 0, stream, ws);
    hipLaunchKernelGGL(k3_main,   dim3(16384), dim3(128),  0, stream, hin, W_map, b_map, ws, out);
}

// Round 3
// 84.187 us; speedup vs baseline: 2.8641x; 2.8641x over previous
//
#include <hip/hip_runtime.h>
#include <math.h>

#define ALPHA 0.2f

typedef __attribute__((ext_vector_type(8))) short bf16x8;
typedef __attribute__((ext_vector_type(4))) float f32x4;
typedef __attribute__((ext_vector_type(4))) unsigned short us4;

// workspace layout (float offsets)
static constexpr size_t WS_ADJ  = 0;      // 1024 f32 adj_n [i][j] (unused by k3 now)
static constexpr size_t WS_WA1  = 1024;   // 32
static constexpr size_t WS_WA2  = 1056;   // 32
static constexpr size_t WS_C12  = 1088;   // 2
static constexpr size_t WS_WMT  = 1152;   // 1024 bf16 = 512 floats: wmT[f][t]
static constexpr size_t WS_ADJT = 1664;   // 1024 bf16: adjT[j][i]
static constexpr size_t WS_S1   = 2560;                    // N*H*W*V
static constexpr size_t WS_S2   = WS_S1 + (size_t)1048576;
static constexpr size_t WS_DEN  = WS_S2 + (size_t)1048576; // [nh][i][j] = 1/denom

__device__ __forceinline__ unsigned short f2bf(float x){
    union { float f; unsigned u; } c; c.f = x;
    unsigned r = c.u + 0x7FFFu + ((c.u >> 16) & 1u);
    return (unsigned short)(r >> 16);
}

__global__ __launch_bounds__(1024) void k0_prep(const float* __restrict__ W_map,
    const float* __restrict__ b_map, const float* __restrict__ a_attn,
    const float* __restrict__ B_adj, float* __restrict__ ws)
{
    __shared__ float lds[1024];
    __shared__ float d12[32];
    int tid = threadIdx.x;
    int i = tid >> 5, j = tid & 31;
    float a = B_adj[tid] + (i == j ? 1.0f : 0.0f);
    lds[tid] = a; __syncthreads();
    for (int s = 512; s > 0; s >>= 1) { if (tid < s) lds[tid] = fmaxf(lds[tid], lds[tid + s]); __syncthreads(); }
    float mx = lds[0]; __syncthreads();
    lds[tid] = a; __syncthreads();
    for (int s = 512; s > 0; s >>= 1) { if (tid < s) lds[tid] = fminf(lds[tid], lds[tid + s]); __syncthreads(); }
    float mn = lds[0]; __syncthreads();
    float nrm = (a - mn) / (mx - mn);
    lds[tid] = nrm; __syncthreads();
    if (tid < 32) {
        float s = 0.f;
        for (int jj = 0; jj < 32; ++jj) s += lds[tid * 32 + jj];
        d12[tid] = 1.0f / sqrtf(s);
    }
    __syncthreads();
    float adjn = d12[i] * nrm * d12[j];
    ws[WS_ADJ + tid] = adjn;
    // adjT bf16 [j][i]
    ((unsigned short*)(ws + WS_ADJT))[j * 32 + i] = f2bf(adjn);
    // wmT bf16 [f][t]  (tid: t = tid>>5, f = tid&31)
    ((unsigned short*)(ws + WS_WMT))[(tid & 31) * 32 + (tid >> 5)] = f2bf(W_map[tid]);
    if (tid < 32) {
        float w1 = 0.f, w2 = 0.f;
        for (int f = 0; f < 32; ++f) {
            w1 += W_map[tid * 32 + f] * a_attn[f];
            w2 += W_map[tid * 32 + f] * a_attn[32 + f];
        }
        ws[WS_WA1 + tid] = w1; ws[WS_WA2 + tid] = w2;
    }
    if (tid == 0) {
        float c1 = 0.f, c2 = 0.f;
        for (int f = 0; f < 32; ++f) { c1 += b_map[f] * a_attn[f]; c2 += b_map[f] * a_attn[32 + f]; }
        ws[WS_C12] = c1; ws[WS_C12 + 1] = c2;
    }
}

// s1/s2[n,h,w,i] = sum_t h[n,h,w,t,i]*wa[t] + c
__global__ __launch_bounds__(256) void k1_scores(const float* __restrict__ hin, float* __restrict__ ws)
{
    __shared__ float lwa1[32], lwa2[32];
    int tid = threadIdx.x;
    if (tid < 32) lwa1[tid] = ws[WS_WA1 + tid];
    else if (tid < 64) lwa2[tid - 32] = ws[WS_WA2 + (tid - 32)];
    __syncthreads();
    float c1 = ws[WS_C12], c2 = ws[WS_C12 + 1];
    int g = tid >> 5, lane = tid & 31;
    long site = (long)blockIdx.x * 8 + g;
    const float* hp = hin + site * 1024;
    float a1 = c1, a2 = c2;
#pragma unroll
    for (int t = 0; t < 32; ++t) {
        float x = hp[t * 32 + lane];
        a1 = fmaf(x, lwa1[t], a1);
        a2 = fmaf(x, lwa2[t], a2);
    }
    ws[WS_S1 + site * 32 + lane] = a1;
    ws[WS_S2 + site * 32 + lane] = a2;
}

// rden[nh,i,j] = 1 / sum_w exp(lrelu(s1[i,w]+s2[j,w]))
__global__ __launch_bounds__(1024) void k2_denom(float* __restrict__ ws)
{
    __shared__ float ls1[2048], ls2[2048];
    int tid = threadIdx.x;
    long nh = blockIdx.x;
    const float* s1 = ws + WS_S1 + nh * 2048;
    const float* s2 = ws + WS_S2 + nh * 2048;
    ls1[tid] = s1[tid]; ls1[tid + 1024] = s1[tid + 1024];
    ls2[tid] = s2[tid]; ls2[tid + 1024] = s2[tid + 1024];
    __syncthreads();
    int i = tid >> 5, j = tid & 31;
    float sum = 0.f;
#pragma unroll
    for (int w = 0; w < 64; ++w) {
        float e = ls1[w * 32 + i] + ls2[w * 32 + j];
        e = e > 0.f ? e : ALPHA * e;
        sum += __expf(e);
    }
    ws[WS_DEN + nh * 1024 + tid] = 1.0f / sum;
}

__device__ __forceinline__ float elu(float x) { return x > 0.f ? x : __expf(x) - 1.0f; }

__device__ __forceinline__ bf16x8 pack8(f32x4 a, f32x4 b){
    bf16x8 r;
    r[0]=(short)f2bf(a[0]); r[1]=(short)f2bf(a[1]); r[2]=(short)f2bf(a[2]); r[3]=(short)f2bf(a[3]);
    r[4]=(short)f2bf(b[0]); r[5]=(short)f2bf(b[1]); r[6]=(short)f2bf(b[2]); r[7]=(short)f2bf(b[3]);
    return r;
}
__device__ __forceinline__ void store_bf4(unsigned short* p, f32x4 v){
    us4 s; s[0]=f2bf(v[0]); s[1]=f2bf(v[1]); s[2]=f2bf(v[2]); s[3]=f2bf(v[3]);
    *(us4*)p = s;
}

// One site per wave; 4 waves/block (same (n,h) row). Three 32x32x32 matmuls via
// mfma_f32_16x16x32_bf16, 2x2 tiles each. at-matrix built in-register.
__global__ __launch_bounds__(256) void k3_main(const float* __restrict__ hin,
    const float* __restrict__ b_map, const float* __restrict__ ws, float* __restrict__ out)
{
    __shared__ float denT[32 * 36];              // [j][i] pad36 (f32, rows 144B)
    __shared__ float hT[4][32 * 36];             // per-wave [v][t] f32 pad36
    __shared__ unsigned short whT[4][32 * 40];   // per-wave [f][j] bf16 pad40 (rows 80B)
    __shared__ unsigned short mtT[4][32 * 40];   // per-wave [j][j'] bf16 pad40

    const int tid = threadIdx.x;
    const int wid = tid >> 6, l = tid & 63;
    const long site = (long)blockIdx.x * 4 + wid;
    const int w = (int)(site & 63);
    const long nh = site >> 6;
    const int hh = (int)(nh & 63);
    const int n = (int)(nh >> 6);
    const int fr = l & 15, g = l >> 4;

    // --- block stage: denT[j][i] = rden[i][j] (transposed) ---
    {
        f32x4 dv = ((const f32x4*)(ws + WS_DEN + nh * 1024))[tid];
        int di = tid >> 3;            // i of element tid*4
        int dj = (tid & 7) * 4;       // j base
        denT[(dj + 0) * 36 + di] = dv[0];
        denT[(dj + 1) * 36 + di] = dv[1];
        denT[(dj + 2) * 36 + di] = dv[2];
        denT[(dj + 3) * 36 + di] = dv[3];
    }
    // --- per-wave stage: hT[v][t] = h_site[t][v] (transposed) ---
    {
        const f32x4* hs = (const f32x4*)(hin + site * 1024);
#pragma unroll
        for (int it = 0; it < 4; ++it) {
            int idx = it * 64 + l;
            f32x4 hv = hs[idx];
            int t = idx >> 3, v0 = (idx & 7) * 4;
            hT[wid][(v0 + 0) * 36 + t] = hv[0];
            hT[wid][(v0 + 1) * 36 + t] = hv[1];
            hT[wid][(v0 + 2) * 36 + t] = hv[2];
            hT[wid][(v0 + 3) * 36 + t] = hv[3];
        }
    }
    // --- constant B operand frags (whole kernel) ---
    bf16x8 wmB[2], adjB[2];
    {
        const short* wmt = (const short*)(ws + WS_WMT);
        const short* adt = (const short*)(ws + WS_ADJT);
#pragma unroll
        for (int q = 0; q < 2; ++q) {
            wmB[q]  = *(const bf16x8*)(wmt + (fr + 16 * q) * 32 + g * 8);
            adjB[q] = *(const bf16x8*)(adt + (fr + 16 * q) * 32 + g * 8);
        }
    }
    float bv[2] = { b_map[fr], b_map[fr + 16] };
    __syncthreads();

    // --- stage 1: Wh[j][f] = sum_t hT[j][t]*wm[t][f] + b[f] ---
    {
        bf16x8 a1[2];
#pragma unroll
        for (int p = 0; p < 2; ++p) {
            f32x4 x0 = *(const f32x4*)&hT[wid][(fr + 16 * p) * 36 + g * 8];
            f32x4 x1 = *(const f32x4*)&hT[wid][(fr + 16 * p) * 36 + g * 8 + 4];
            a1[p] = pack8(x0, x1);
        }
#pragma unroll
        for (int p = 0; p < 2; ++p)
#pragma unroll
            for (int q = 0; q < 2; ++q) {
                f32x4 c = { bv[q], bv[q], bv[q], bv[q] };
                c = __builtin_amdgcn_mfma_f32_16x16x32_bf16(a1[p], wmB[q], c, 0, 0, 0);
                // C: col f = fr+16q, rows j = 4g..4g+3 (+16p) -> store transposed [f][j]
                store_bf4(&whT[wid][(fr + 16 * q) * 40 + 4 * g + 16 * p], c);
            }
    }

    // --- stage 2: M[j'][j] = sum_i at[i][j']*adj[i][j], at built in-register ---
    {
        f32x4 s1a = *(const f32x4*)(ws + WS_S1 + site * 32 + g * 8);
        f32x4 s1b = *(const f32x4*)(ws + WS_S1 + site * 32 + g * 8 + 4);
        float s2v[2] = { ws[WS_S2 + site * 32 + fr], ws[WS_S2 + site * 32 + fr + 16] };
        bf16x8 a2[2];
#pragma unroll
        for (int p = 0; p < 2; ++p) {
            f32x4 d0 = *(const f32x4*)&denT[(fr + 16 * p) * 36 + g * 8];
            f32x4 d1 = *(const f32x4*)&denT[(fr + 16 * p) * 36 + g * 8 + 4];
            f32x4 t0, t1;
#pragma unroll
            for (int e = 0; e < 4; ++e) {
                float ea = s1a[e] + s2v[p]; ea = ea > 0.f ? ea : ALPHA * ea;
                float eb = s1b[e] + s2v[p]; eb = eb > 0.f ? eb : ALPHA * eb;
                t0[e] = __expf(ea) * d0[e];
                t1[e] = __expf(eb) * d1[e];
            }
            a2[p] = pack8(t0, t1);
        }
#pragma unroll
        for (int p = 0; p < 2; ++p)
#pragma unroll
            for (int q = 0; q < 2; ++q) {
                f32x4 c = { 0.f, 0.f, 0.f, 0.f };
                c = __builtin_amdgcn_mfma_f32_16x16x32_bf16(a2[p], adjB[q], c, 0, 0, 0);
                // C: col j = fr+16q, rows j' = 4g..+3 (+16p) -> store [j][j']
                store_bf4(&mtT[wid][(fr + 16 * q) * 40 + 4 * g + 16 * p], c);
            }
    }

    // --- stage 3: O[f][j] = sum_j' WhT[f][j'] * M[j'][j] ---
    {
        bf16x8 a3[2], b3[2];
#pragma unroll
        for (int p = 0; p < 2; ++p)
            a3[p] = *(const bf16x8*)&whT[wid][(fr + 16 * p) * 40 + g * 8];
#pragma unroll
        for (int q = 0; q < 2; ++q)
            b3[q] = *(const bf16x8*)&mtT[wid][(fr + 16 * q) * 40 + g * 8];
        const int hhi = hh >> 5, f3 = hh & 31;
#pragma unroll
        for (int p = 0; p < 2; ++p)
#pragma unroll
            for (int q = 0; q < 2; ++q) {
                f32x4 c = { 0.f, 0.f, 0.f, 0.f };
                c = __builtin_amdgcn_mfma_f32_16x16x32_bf16(a3[p], b3[q], c, 0, 0, 0);
                // C: col j = fr+16q, rows f = 4g+r+16p
#pragma unroll
                for (int r = 0; r < 4; ++r) {
                    int f = 16 * p + 4 * g + r;
                    int w3 = f * 2 + hhi;
                    out[((((long)n * 64 + w) * 64 + w3) * 32 + f3) * 32 + fr + 16 * q] = elu(c[r]);
                }
            }
    }
}

extern "C" void kernel_launch(void* const* d_in, const int* in_sizes, int n_in,
                              void* d_out, int out_size, void* d_ws, size_t ws_size,
                              hipStream_t stream) {
    (void)in_sizes; (void)n_in; (void)out_size; (void)ws_size;
    const float* hin    = (const float*)d_in[0];
    const float* W_map  = (const float*)d_in[1];
    const float* b_map  = (const float*)d_in[2];
    const float* a_attn = (const float*)d_in[3];
    const float* B_adj  = (const float*)d_in[4];
    float* out = (float*)d_out;
    float* ws  = (float*)d_ws;

    hipLaunchKernelGGL(k0_prep,   dim3(1),    dim3(1024), 0, stream, W_map, b_map, a_attn, B_adj, ws);
    hipLaunchKernelGGL(k1_scores, dim3(4096), dim3(256),  0, stream, hin, ws);
    hipLaunchKernelGGL(k2_denom,  dim3(512),  dim3(1024), 0, stream, ws);
    hipLaunchKernelGGL(k3_main,   dim3(8192), dim3(256),  0, stream, hin, b_map, ws, out);
}